// Round 10
// baseline (323.441 us; speedup 1.0000x reference)
//
#include <hip/hip_runtime.h>

#define N_CODES 512
#define D 32
#define NVEC (8192 * 64)          // 524288 vectors
#define ZQ_ELEMS (NVEC * D)
#define NBLK (NVEC / 256)         // 2048 main blocks
#define MARGIN_TRIG 7e-5f
#define SA (-1.0f / 16.0f)        // A = SA*z   (power of 2, exact)
#define SB (32.0f)                // B = SB*w   -> A*B sums to -2 z.w
#define KMASK 0xFFFFFFE0u         // clear 5 low mantissa bits for t-index

typedef _Float16 half8 __attribute__((ext_vector_type(8)));
typedef float f32x4 __attribute__((ext_vector_type(4)));

// ws: @8 uint flagcnt | @64 float ww[512] | @2112 float ww1[512] (1+||w||^2)
//     | @4160 bfrag (32768) | @36928 double partials[2048] | @53312 worklist
#define WW1_OFF 2112
#define BFRAG_OFF 4160
#define PART_OFF 36928
#define WL_OFF 53312

__global__ void vq_prep(const float* __restrict__ cb, float* __restrict__ ww,
                        float* __restrict__ ww1, half8* __restrict__ bfrag,
                        unsigned* __restrict__ flagcnt) {
    int gid = blockIdx.x * 256 + threadIdx.x;   // 8 x 256 = 2048
    if (gid == 0) *flagcnt = 0u;
    if (gid >= 2048) return;
    int t = gid >> 6, l = gid & 63;
    int code = t * 16 + (l & 15), koff = (l >> 4) * 8;
    const float* w = cb + (size_t)code * D + koff;
    half8 h;
#pragma unroll
    for (int j = 0; j < 8; ++j) h[j] = (_Float16)(SB * w[j]);
    bfrag[t * 64 + l] = h;                      // MFMA B-fragment lane order
    if (koff == 0) {                            // platonic ||w||^2 -> f32
        const float* wr = cb + (size_t)code * D;
        double s = 0.0;
#pragma unroll
        for (int d = 0; d < D; ++d) s = fma((double)wr[d], (double)wr[d], s);
        ww[code] = (float)s;                    // exact, for fixup formula
        ww1[code] = (float)(1.0 + s);           // C-init (+1 => scores positive)
    }
}

__global__ __launch_bounds__(256, 6) void vq_main(
        const float* __restrict__ z, const float* __restrict__ cbf,
        const half8* __restrict__ bfrag_g, const float* __restrict__ ww1_g,
        float* __restrict__ zq, float* __restrict__ idxo,
        double* __restrict__ partials, unsigned* __restrict__ flagcnt,
        int* __restrict__ worklist, int wl_cap) {
    __shared__ float lds_ww1[512];
    __shared__ __align__(16) float4 scratch[256];   // (m1-1, m2-1, idx, zz)
    __shared__ double wsum[4];
    const int tid = threadIdx.x;

    lds_ww1[tid] = ww1_g[tid];
    lds_ww1[tid + 256] = ww1_g[tid + 256];

    const int l = tid & 63, wv = tid >> 6;
    const int g16 = l & 15, kg = l >> 4, koff = kg * 8;
    const int vblock = blockIdx.x * 256;         // block owns 256 rows

    const half8* bl = bfrag_g + l;               // lane-fixed B base

    __syncthreads();   // ww1 staged

#pragma unroll 1
    for (int mt = 0; mt < 4; ++mt) {
        const int rbase = wv * 64 + mt * 16;     // rows rbase..rbase+15 (in block)
        const float* zp = z + (size_t)(vblock + rbase + g16) * D + koff;
        float4 a0 = *(const float4*)zp;
        float4 a1 = *(const float4*)(zp + 4);
        half8 A;
        A[0] = (_Float16)(a0.x * SA); A[1] = (_Float16)(a0.y * SA);
        A[2] = (_Float16)(a0.z * SA); A[3] = (_Float16)(a0.w * SA);
        A[4] = (_Float16)(a1.x * SA); A[5] = (_Float16)(a1.y * SA);
        A[6] = (_Float16)(a1.z * SA); A[7] = (_Float16)(a1.w * SA);
        float ss = 0.f;
        ss = fmaf(a0.x, a0.x, ss); ss = fmaf(a0.y, a0.y, ss);
        ss = fmaf(a0.z, a0.z, ss); ss = fmaf(a0.w, a0.w, ss);
        ss = fmaf(a1.x, a1.x, ss); ss = fmaf(a1.y, a1.y, ss);
        ss = fmaf(a1.z, a1.z, ss); ss = fmaf(a1.w, a1.w, ss);
        ss += __shfl_xor(ss, 16, 64);            // sum the 4 koff chunks
        ss += __shfl_xor(ss, 32, 64);

        unsigned m1u[4], m2u[4];
#pragma unroll
        for (int r = 0; r < 4; ++r) { m1u[r] = 0xFFFFFFFFu; m2u[r] = 0xFFFFFFFFu; }

        // scores positive (C = 1+||w||^2, |2 z.w| < 0.5) -> uint-orderable keys
#pragma unroll
        for (int p = 0; p < 16; ++p) {
            half8 B0 = bl[(2 * p) * 64];
            half8 B1 = bl[(2 * p + 1) * 64];
            float c0 = lds_ww1[(2 * p) * 16 + g16];
            float c1 = lds_ww1[(2 * p + 1) * 16 + g16];
            f32x4 acc0 = {c0, c0, c0, c0};
            acc0 = __builtin_amdgcn_mfma_f32_16x16x32_f16(A, B0, acc0, 0, 0, 0);
            f32x4 acc1 = {c1, c1, c1, c1};
            acc1 = __builtin_amdgcn_mfma_f32_16x16x32_f16(A, B1, acc1, 0, 0, 0);
#pragma unroll
            for (int r = 0; r < 4; ++r) {
                unsigned k0 = (__float_as_uint(acc0[r]) & KMASK) | (unsigned)(2 * p);
                unsigned k1 = (__float_as_uint(acc1[r]) & KMASK) | (unsigned)(2 * p + 1);
                unsigned med;
                asm("v_med3_u32 %0, %1, %2, %3"
                    : "=v"(med) : "v"(m1u[r]), "v"(k0), "v"(k1));
                asm("v_min3_u32 %0, %1, %2, %3"
                    : "=v"(m1u[r]) : "v"(m1u[r]), "v"(k0), "v"(k1));
                m2u[r] = m2u[r] < med ? m2u[r] : med;    // v_min_u32
            }
        }

        // unpack + reduce across the 16 code-lanes of each row-group
#pragma unroll
        for (int r = 0; r < 4; ++r) {
            float a1v = __uint_as_float(m1u[r] & KMASK);
            float a2v = __uint_as_float(m2u[r] & KMASK);
            int ai = (int)(m1u[r] & 31u) * 16 + g16;
#pragma unroll
            for (int dd = 1; dd <= 8; dd <<= 1) {
                float o1 = __shfl_xor(a1v, dd, 64);
                float o2 = __shfl_xor(a2v, dd, 64);
                int oi = __shfl_xor(ai, dd, 64);
                a2v = fminf(fminf(a2v, o2), fmaxf(a1v, o1));
                bool take = (o1 < a1v) || (o1 == a1v && oi < ai);
                ai = take ? oi : ai;
                a1v = fminf(a1v, o1);
            }
            if (g16 == r) {
                float* sp = (float*)&scratch[rbase + 4 * kg + r];
                sp[0] = a1v - 1.0f;              // s_win (undo +1 baked in C)
                sp[1] = a2v - 1.0f;
                sp[2] = __int_as_float(ai);
            }
        }
        if (kg == 0)
            ((float*)&scratch[rbase + g16])[3] = ss;   // ||z||^2
    }
    __syncthreads();

    // ---- epilogue (block scope; no f64, no global atomics except worklist) ----
    float4 my = scratch[tid];                    // row tid of this block

    // near-tie rows -> global worklist (resolved by vq_fixup kernel)
    {
        bool flag = (my.y - my.x) <= MARGIN_TRIG;
        unsigned long long mask = __ballot(flag);
        if (mask) {
            int base = 0;
            if (l == 0) base = (int)atomicAdd(flagcnt, (unsigned)__popcll(mask));
            base = __shfl(base, 0, 64);
            if (flag) {
                int pos = base + (int)__popcll(mask & ((1ull << l) - 1ull));
                if (pos < wl_cap) worklist[pos] = vblock + tid;
            }
        }
    }

    // loss: ||z-q||^2 = ||z||^2 + s_win ; block-level reduce -> partials[bid]
    {
        double contrib = (double)my.x + (double)my.w;
#pragma unroll
        for (int off = 32; off; off >>= 1) contrib += __shfl_down(contrib, off, 64);
        if (l == 0) wsum[wv] = contrib;
    }
    __syncthreads();
    if (tid == 0) partials[blockIdx.x] = wsum[0] + wsum[1] + wsum[2] + wsum[3];

    // indices: 1KB contiguous per block
    idxo[vblock + tid] = (float)__float_as_int(my.z);
    // z_q: 256 threads x 8 iters cover 256 rows x 32 floats, fully contiguous
    {
        const float4* cb4 = (const float4*)cbf;
        float4* zq4 = (float4*)zq;
        const int c = tid & 7;
#pragma unroll
        for (int it = 0; it < 8; ++it) {
            int r = it * 32 + (tid >> 3);
            int win = __float_as_int(((const float*)scratch)[r * 4 + 2]);
            float4 val = cb4[(size_t)win * 8 + c];
            zq4[(size_t)(vblock + r) * 8 + c] = val;
        }
    }
}

// cold path: exact wave-parallel rescan of flagged rows + (block 0) loss final
__global__ __launch_bounds__(256, 2) void vq_fixup(
        const float* __restrict__ z, const float* __restrict__ cbf,
        const float* __restrict__ c32g,
        float* __restrict__ zq, float* __restrict__ idxo,
        const unsigned* __restrict__ flagcnt,
        const int* __restrict__ worklist, int wl_cap,
        const double* __restrict__ partials, float* __restrict__ loss_out) {
    if (blockIdx.x == 0) {                      // final loss reduction
        const int tid = threadIdx.x;
        double s = 0.0;
#pragma unroll
        for (int i = 0; i < NBLK / 256; ++i) s += partials[i * 256 + tid];
#pragma unroll
        for (int off = 32; off; off >>= 1) s += __shfl_down(s, off, 64);
        __shared__ double w4[4];
        if ((tid & 63) == 0) w4[tid >> 6] = s;
        __syncthreads();
        if (tid == 0)
            *loss_out = (float)(1.25 * (w4[0] + w4[1] + w4[2] + w4[3])
                                / (double)ZQ_ELEMS);
    }

    int cnt = (int)*flagcnt; if (cnt > wl_cap) cnt = wl_cap;
    const int l = threadIdx.x & 63;
    const int wave = (blockIdx.x * blockDim.x + threadIdx.x) >> 6;
    const int nwaves = (gridDim.x * blockDim.x) >> 6;

    for (int e = wave; e < cnt; e += nwaves) {
        int v = worklist[e];
        const float* zv = z + (size_t)v * D;        // uniform addr -> broadcast
        float4 zr[8];                               // hoist z once (32 regs)
#pragma unroll
        for (int q = 0; q < 8; ++q) zr[q] = *(const float4*)(zv + q * 4);
        double Ad = 0.0;
#pragma unroll
        for (int q = 0; q < 8; ++q) {
            Ad = fma((double)zr[q].x, (double)zr[q].x, Ad);
            Ad = fma((double)zr[q].y, (double)zr[q].y, Ad);
            Ad = fma((double)zr[q].z, (double)zr[q].z, Ad);
            Ad = fma((double)zr[q].w, (double)zr[q].w, Ad);
        }
        float Af = (float)Ad;
        float best = 1e30f; int bi = 0;
#pragma unroll 2
        for (int j = 0; j < 8; ++j) {
            int c = l * 8 + j;                      // lane-major => index-ordered
            const float* w = cbf + (size_t)c * D;
            double bd = 0.0;
#pragma unroll
            for (int q = 0; q < 8; ++q) {
                float4 wq = *(const float4*)(w + q * 4);
                bd = fma((double)zr[q].x, (double)wq.x, bd);
                bd = fma((double)zr[q].y, (double)wq.y, bd);
                bd = fma((double)zr[q].z, (double)wq.z, bd);
                bd = fma((double)zr[q].w, (double)wq.w, bd);
            }
            float B32 = (float)bd;                  // platonic dot
            float dq = __fadd_rn(__fsub_rn(Af, __fmul_rn(2.0f, B32)), c32g[c]);
            if (dq < best) { best = dq; bi = c; }
        }
#pragma unroll
        for (int dd = 1; dd < 64; dd <<= 1) {
            float ob = __shfl_xor(best, dd, 64);
            int obi = __shfl_xor(bi, dd, 64);
            bool take = (ob < best) || (ob == best && obi < bi);
            best = take ? ob : best; bi = take ? obi : bi;
        }
        if (l == 0) idxo[v] = (float)bi;
        if (l < 8) {                                // one full 128B line
            float4 val = ((const float4*)cbf)[(size_t)bi * 8 + l];
            ((float4*)zq)[(size_t)v * 8 + l] = val;
        }
    }
}

extern "C" void kernel_launch(void* const* d_in, const int* in_sizes, int n_in,
                              void* d_out, int out_size, void* d_ws, size_t ws_size,
                              hipStream_t stream) {
    const float* z  = (const float*)d_in[0];
    const float* cb = (const float*)d_in[1];
    float* out  = (float*)d_out;
    float* zq   = out;
    float* idxo = out + ZQ_ELEMS;
    float* loss = out + ZQ_ELEMS + NVEC;
    unsigned* flagcnt = (unsigned*)((char*)d_ws + 8);
    float*    ww      = (float*)((char*)d_ws + 64);
    float*    ww1     = (float*)((char*)d_ws + WW1_OFF);
    half8*    bfrag   = (half8*)((char*)d_ws + BFRAG_OFF);
    double*   partials = (double*)((char*)d_ws + PART_OFF);
    int*      worklist = (int*)((char*)d_ws + WL_OFF);
    long long avail = (long long)ws_size - WL_OFF;
    int wl_cap = avail > 0 ? (int)(avail / 4 < NVEC ? avail / 4 : NVEC) : 0;

    vq_prep<<<8, 256, 0, stream>>>(cb, ww, ww1, bfrag, flagcnt);
    vq_main<<<NBLK, 256, 0, stream>>>(z, cb, bfrag, ww1, zq, idxo,
                                      partials, flagcnt, worklist, wl_cap);
    vq_fixup<<<512, 256, 0, stream>>>(z, cb, ww, zq, idxo, flagcnt,
                                      worklist, wl_cap, partials, loss);
}

// Round 11
// 241.987 us; speedup vs baseline: 1.3366x; 1.3366x over previous
//
#include <hip/hip_runtime.h>

#define N_CODES 512
#define D 32
#define NVEC (8192 * 64)          // 524288 vectors
#define ZQ_ELEMS (NVEC * D)
#define NBLK (NVEC / 256)         // 2048 main blocks
#define MARGIN_TRIG 7e-5f
#define SA (-1.0f / 16.0f)        // A = SA*z   (power of 2, exact)
#define SB (32.0f)                // B = SB*w   -> A*B sums to -2 z.w
#define KMASK 0xFFFFFFE0u         // clear 5 low mantissa bits for t-index
#define FLAG_OFS 1024             // idx += 1024 marks "needs exact rescan"

typedef _Float16 half8 __attribute__((ext_vector_type(8)));
typedef float f32x4 __attribute__((ext_vector_type(4)));

// ws: @64 float ww[512] | @2112 float ww1[512] | @4160 bfrag (32768)
//     | @36928 double partials[2048]
#define WW1_OFF 2112
#define BFRAG_OFF 4160
#define PART_OFF 36928

__global__ void vq_prep(const float* __restrict__ cb, float* __restrict__ ww,
                        float* __restrict__ ww1, half8* __restrict__ bfrag) {
    int gid = blockIdx.x * 256 + threadIdx.x;   // 8 x 256 = 2048
    if (gid >= 2048) return;
    int t = gid >> 6, l = gid & 63;
    int code = t * 16 + (l & 15), koff = (l >> 4) * 8;
    const float* w = cb + (size_t)code * D + koff;
    half8 h;
#pragma unroll
    for (int j = 0; j < 8; ++j) h[j] = (_Float16)(SB * w[j]);
    bfrag[t * 64 + l] = h;                      // MFMA B-fragment lane order
    if (koff == 0) {                            // platonic ||w||^2 -> f32
        const float* wr = cb + (size_t)code * D;
        double s = 0.0;
#pragma unroll
        for (int d = 0; d < D; ++d) s = fma((double)wr[d], (double)wr[d], s);
        ww[code] = (float)s;                    // exact, for fixup formula
        ww1[code] = (float)(1.0 + s);           // C-init (+1 => scores positive)
    }
}

// wave owns 128 codes (8 B-fragments, register-resident); loops 16 row-tiles.
__global__ __launch_bounds__(256, 5) void vq_main(
        const float* __restrict__ z, const float* __restrict__ cbf,
        const half8* __restrict__ bfrag_g, const float* __restrict__ ww1_g,
        float* __restrict__ zq, float* __restrict__ idxo,
        double* __restrict__ partials) {
    __shared__ __align__(16) float4 pw[256][4];   // per-row per-wave (m1,m2,ai,-)
    __shared__ float zz_s[256];
    __shared__ int win_s[256];
    __shared__ double wsum[4];
    const int tid = threadIdx.x;
    const int l = tid & 63, wv = tid >> 6;
    const int g16 = l & 15, kg = l >> 4, koff = kg * 8;
    const int vblock = blockIdx.x * 256;          // block owns 256 rows

    // this wave's 8 code-tiles: t = wv*8 + j  (B + C-init held in registers)
    half8 Breg[8];
    float cin[8];
#pragma unroll
    for (int j = 0; j < 8; ++j) {
        Breg[j] = bfrag_g[(size_t)(wv * 8 + j) * 64 + l];
        cin[j] = ww1_g[(wv * 8 + j) * 16 + g16];
    }

#pragma unroll 1
    for (int tt = 0; tt < 16; ++tt) {
        const float* zp = z + (size_t)(vblock + tt * 16 + g16) * D + koff;
        float4 a0 = *(const float4*)zp;
        float4 a1 = *(const float4*)(zp + 4);
        half8 A;
        A[0] = (_Float16)(a0.x * SA); A[1] = (_Float16)(a0.y * SA);
        A[2] = (_Float16)(a0.z * SA); A[3] = (_Float16)(a0.w * SA);
        A[4] = (_Float16)(a1.x * SA); A[5] = (_Float16)(a1.y * SA);
        A[6] = (_Float16)(a1.z * SA); A[7] = (_Float16)(a1.w * SA);
        if (wv == 0) {                            // ||z||^2 (wave 0 only)
            float ss = 0.f;
            ss = fmaf(a0.x, a0.x, ss); ss = fmaf(a0.y, a0.y, ss);
            ss = fmaf(a0.z, a0.z, ss); ss = fmaf(a0.w, a0.w, ss);
            ss = fmaf(a1.x, a1.x, ss); ss = fmaf(a1.y, a1.y, ss);
            ss = fmaf(a1.z, a1.z, ss); ss = fmaf(a1.w, a1.w, ss);
            ss += __shfl_xor(ss, 16, 64);
            ss += __shfl_xor(ss, 32, 64);
            if (kg == 0) zz_s[tt * 16 + l] = ss;
        }

        unsigned m1u[4], m2u[4];
#pragma unroll
        for (int r = 0; r < 4; ++r) { m1u[r] = 0xFFFFFFFFu; m2u[r] = 0xFFFFFFFFu; }

#pragma unroll
        for (int p = 0; p < 4; ++p) {
            f32x4 acc0, acc1;
            float c0 = cin[2 * p], c1 = cin[2 * p + 1];
            acc0[0] = c0; acc0[1] = c0; acc0[2] = c0; acc0[3] = c0;
            acc0 = __builtin_amdgcn_mfma_f32_16x16x32_f16(A, Breg[2 * p], acc0, 0, 0, 0);
            acc1[0] = c1; acc1[1] = c1; acc1[2] = c1; acc1[3] = c1;
            acc1 = __builtin_amdgcn_mfma_f32_16x16x32_f16(A, Breg[2 * p + 1], acc1, 0, 0, 0);
            unsigned t0 = (unsigned)(wv * 8 + 2 * p), t1 = t0 + 1;
#pragma unroll
            for (int r = 0; r < 4; ++r) {
                unsigned k0 = (__float_as_uint(acc0[r]) & KMASK) | t0;
                unsigned k1 = (__float_as_uint(acc1[r]) & KMASK) | t1;
                unsigned med;
                asm("v_med3_u32 %0, %1, %2, %3"
                    : "=v"(med) : "v"(m1u[r]), "v"(k0), "v"(k1));
                asm("v_min3_u32 %0, %1, %2, %3"
                    : "=v"(m1u[r]) : "v"(m1u[r]), "v"(k0), "v"(k1));
                m2u[r] = m2u[r] < med ? m2u[r] : med;
            }
        }

        // unpack + reduce over the 16 code-columns (g16) of this wave's tiles
#pragma unroll
        for (int r = 0; r < 4; ++r) {
            float a1v = __uint_as_float(m1u[r] & KMASK);
            float a2v = __uint_as_float(m2u[r] & KMASK);
            int ai = (int)(m1u[r] & 31u) * 16 + g16;
#pragma unroll
            for (int dd = 1; dd <= 8; dd <<= 1) {
                float o1 = __shfl_xor(a1v, dd, 64);
                float o2 = __shfl_xor(a2v, dd, 64);
                int oi = __shfl_xor(ai, dd, 64);
                a2v = fminf(fminf(a2v, o2), fmaxf(a1v, o1));
                bool take = (o1 < a1v) || (o1 == a1v && oi < ai);
                ai = take ? oi : ai;
                a1v = fminf(a1v, o1);
            }
            if (g16 == r)   // holder writes row tt*16 + 4*kg + r, slot wv
                pw[tt * 16 + 4 * kg + r][wv] =
                    make_float4(a1v, a2v, __int_as_float(ai), 0.f);
        }
    }
    __syncthreads();

    // ---- epilogue: merge 4 wave-partials per row (thread tid = row) ----
    float b1 = 1e30f, b2 = 1e30f; int bai = 0x7FFFFFFF;
#pragma unroll
    for (int w = 0; w < 4; ++w) {
        float4 p = pw[tid][w];
        float v1 = p.x, v2 = p.y; int ai = __float_as_int(p.z);
        float nb2 = fminf(fmaxf(b1, v1), fminf(b2, v2));
        bool take = (v1 < b1) || (v1 == b1 && ai < bai);
        bai = take ? ai : bai;
        b1 = fminf(b1, v1);
        b2 = nb2;
    }

    // loss: ||z-q||^2 = ||z||^2 + (m1 - 1)
    {
        double contrib = ((double)b1 - 1.0) + (double)zz_s[tid];
#pragma unroll
        for (int off = 32; off; off >>= 1) contrib += __shfl_down(contrib, off, 64);
        if (l == 0) wsum[wv] = contrib;
    }

    // idx (+1024 marks near-tie rows for the fixup pass); no atomics anywhere
    bool flag = (b2 - b1) <= MARGIN_TRIG;
    idxo[vblock + tid] = (float)(bai + (flag ? FLAG_OFS : 0));
    win_s[tid] = bai;
    __syncthreads();
    if (tid == 0) partials[blockIdx.x] = wsum[0] + wsum[1] + wsum[2] + wsum[3];

    // z_q: 256 threads x 8 iters cover 256 rows x 32 floats, fully contiguous
    {
        const float4* cb4 = (const float4*)cbf;
        float4* zq4 = (float4*)zq;
        const int c = tid & 7;
#pragma unroll
        for (int it = 0; it < 8; ++it) {
            int r = it * 32 + (tid >> 3);
            int win = win_s[r];
            float4 val = cb4[(size_t)win * 8 + c];
            zq4[(size_t)(vblock + r) * 8 + c] = val;
        }
    }
}

// cold path: scan idxo for flagged rows (>=1024), exact wave-parallel rescan.
// Also (block 0) final loss reduction.
__global__ __launch_bounds__(256, 2) void vq_fixup(
        const float* __restrict__ z, const float* __restrict__ cbf,
        const float* __restrict__ c32g,
        float* __restrict__ zq, float* __restrict__ idxo,
        const double* __restrict__ partials, float* __restrict__ loss_out) {
    if (blockIdx.x == 0) {                      // final loss reduction
        const int tid = threadIdx.x;
        double s = 0.0;
#pragma unroll
        for (int i = 0; i < NBLK / 256; ++i) s += partials[i * 256 + tid];
#pragma unroll
        for (int off = 32; off; off >>= 1) s += __shfl_down(s, off, 64);
        __shared__ double w4[4];
        if ((tid & 63) == 0) w4[tid >> 6] = s;
        __syncthreads();
        if (tid == 0)
            *loss_out = (float)(1.25 * (w4[0] + w4[1] + w4[2] + w4[3])
                                / (double)ZQ_ELEMS);
    }

    const int l = threadIdx.x & 63;
    const int wave = (blockIdx.x * blockDim.x + threadIdx.x) >> 6;
    const int nwaves = (gridDim.x * blockDim.x) >> 6;

    for (int ch = wave; ch < NVEC / 64; ch += nwaves) {
        int v0 = ch * 64;
        float fv = idxo[v0 + l];
        unsigned long long m = __ballot(fv >= (float)FLAG_OFS);
        while (m) {
            int b = __builtin_ctzll(m); m &= m - 1;
            int v = v0 + b;
            const float* zv = z + (size_t)v * D;    // uniform addr -> broadcast
            float4 zr[8];                           // hoist z once (32 regs)
#pragma unroll
            for (int q = 0; q < 8; ++q) zr[q] = *(const float4*)(zv + q * 4);
            double Ad = 0.0;
#pragma unroll
            for (int q = 0; q < 8; ++q) {
                Ad = fma((double)zr[q].x, (double)zr[q].x, Ad);
                Ad = fma((double)zr[q].y, (double)zr[q].y, Ad);
                Ad = fma((double)zr[q].z, (double)zr[q].z, Ad);
                Ad = fma((double)zr[q].w, (double)zr[q].w, Ad);
            }
            float Af = (float)Ad;
            float best = 1e30f; int bi = 0;
#pragma unroll 2
            for (int j = 0; j < 8; ++j) {
                int c = l * 8 + j;                  // lane-major => index-ordered
                const float* w = cbf + (size_t)c * D;
                double bd = 0.0;
#pragma unroll
                for (int q = 0; q < 8; ++q) {
                    float4 wq = *(const float4*)(w + q * 4);
                    bd = fma((double)zr[q].x, (double)wq.x, bd);
                    bd = fma((double)zr[q].y, (double)wq.y, bd);
                    bd = fma((double)zr[q].z, (double)wq.z, bd);
                    bd = fma((double)zr[q].w, (double)wq.w, bd);
                }
                float B32 = (float)bd;              // platonic dot
                float dq = __fadd_rn(__fsub_rn(Af, __fmul_rn(2.0f, B32)), c32g[c]);
                if (dq < best) { best = dq; bi = c; }
            }
#pragma unroll
            for (int dd = 1; dd < 64; dd <<= 1) {
                float ob = __shfl_xor(best, dd, 64);
                int obi = __shfl_xor(bi, dd, 64);
                bool take = (ob < best) || (ob == best && obi < bi);
                best = take ? ob : best; bi = take ? obi : bi;
            }
            if (l == 0) idxo[v] = (float)bi;        // clears the +1024 flag too
            if (l < 8) {                            // one full 128B line
                float4 val = ((const float4*)cbf)[(size_t)bi * 8 + l];
                ((float4*)zq)[(size_t)v * 8 + l] = val;
            }
        }
    }
}

extern "C" void kernel_launch(void* const* d_in, const int* in_sizes, int n_in,
                              void* d_out, int out_size, void* d_ws, size_t ws_size,
                              hipStream_t stream) {
    const float* z  = (const float*)d_in[0];
    const float* cb = (const float*)d_in[1];
    float* out  = (float*)d_out;
    float* zq   = out;
    float* idxo = out + ZQ_ELEMS;
    float* loss = out + ZQ_ELEMS + NVEC;
    float*  ww   = (float*)((char*)d_ws + 64);
    float*  ww1  = (float*)((char*)d_ws + WW1_OFF);
    half8*  bfrag = (half8*)((char*)d_ws + BFRAG_OFF);
    double* partials = (double*)((char*)d_ws + PART_OFF);

    vq_prep<<<8, 256, 0, stream>>>(cb, ww, ww1, bfrag);
    vq_main<<<NBLK, 256, 0, stream>>>(z, cb, bfrag, ww1, zq, idxo, partials);
    vq_fixup<<<512, 256, 0, stream>>>(z, cb, ww, zq, idxo, partials, loss);
}